// Round 8
// baseline (799.829 us; speedup 1.0000x reference)
//
#include <hip/hip_runtime.h>

// Encoder block: LN1 -> QKV -> per-token head-mix attention -> scramble ->
// WO -> +x,LN1 -> W1+GELU (2 halves) -> W2 accum (+b2,+q2) -> LN2 in-place.
//
// Two GEMM geometries:
//  gemm256 (rev 5, SINGLE-PHASE): 256x256 / BK=64 / 8 waves / 128 KiB LDS.
//    r4's 4-phase loop (8 barriers/K-tile) serialized LDS and MFMA pipes
//    within each phase: 620 cyc MFMA content / ~1450 cyc phase = 43% ->
//    measured MfmaUtil 37.6%. Rev 5 collapses to 2 barriers/K-tile:
//      read ALL 24 frags (a0,b0,b1,a1) ->
//      48 MFMA (q00,q01,q11)  [compiler emits counted lgkmcnt: first MFMAs
//                              start after 12 reads; tail reads overlap]
//      lgkmcnt(0) (free: reads consumed) ; barrier #1
//      stage B(u+2)+A(u+2) [8 gloads, current-parity: legal, all reads done]
//      16 MFMA q10 (register-only, overlaps gloads)
//      vmcnt(8) counted (tile u+1 landed - issued a full tile ago;
//                        u+2's 8 stay in flight) ; barrier #2
//    Race discipline unchanged from rev3/4 (verified): staging overwrites a
//    region only after a barrier that postdates all reads of that region.
//  gemm128: 128x256 / BK=32 / 8 waves / 48 KiB LDS, (512,4) -> 2 blocks/CU
//    (VGPR budget 128; (512,6) spilled acc -> 2.4 GB scratch, r5).
//    Same single-phase structure. Used for N=1024/2048 shapes.
//  XCD mapping (both): bm-banded / bn-fastest (A band L2-resident per XCD).
//
// attn_k: LDS rows padded to 65 floats (16-way bank conflict fix, r7).
// wconv_all: all 7 weight conversions in one launch (r7).
// Workspace footprint: 152 MB (d_out doubles as the f32 residual buffer).

typedef __attribute__((ext_vector_type(8))) short s16x8;
typedef __attribute__((ext_vector_type(4))) short s16x4;
typedef __attribute__((ext_vector_type(4))) float f32x4;

__device__ __forceinline__ short f2bf(float x) {
  unsigned u = __builtin_bit_cast(unsigned, x);
  u = (u + 0x7FFFu + ((u >> 16) & 1u)) >> 16;
  return (short)u;
}
__device__ __forceinline__ float bf2f(short s) {
  unsigned u = ((unsigned)(unsigned short)s) << 16;
  return __builtin_bit_cast(float, u);
}

__device__ __forceinline__ void ld_g2l16(const short* g, const short* l) {
  __builtin_amdgcn_global_load_lds(
      (const __attribute__((address_space(1))) void*)g,
      (__attribute__((address_space(3))) void*)l, 16, 0, 0);
}

// Guaranteed-DS vector read: explicit addrspace(3) so codegen emits
// ds_read_b128 (never flat_load).
__device__ __forceinline__ s16x8 lds_read8(const short* smem, int off) {
  const __attribute__((address_space(3))) short* p =
      (const __attribute__((address_space(3))) short*)smem;
  return *(const __attribute__((address_space(3))) s16x8*)(p + off);
}

// Fast GELU (tanh form via v_exp_f32; |err| ~1e-3 << bf16 noise).
__device__ __forceinline__ float fast_gelu(float v) {
  float y = 0.7978845608f * (v + 0.044715f * v * v * v);
  float ay = fabsf(y);
  float t = __expf(-2.0f * ay);
  float th = (1.0f - t) * __frcp_rn(1.0f + t);
  th = (y >= 0.f) ? th : -th;
  return 0.5f * v * (1.0f + th);
}

#define MFMA16(va, vb, vc) \
  __builtin_amdgcn_mfma_f32_16x16x32_bf16(va, vb, vc, 0, 0, 0)

// ---------------------------------------------------------------------------
// gemm256: C[M,N] = A[M,K] @ BT[N,K]^T. M=16384. N,K multiples of 256.
// EPI: 0 bf16 store; 1 f32 store; 2 +bias,GELU,bf16; 4 f32 accum (+bias).
// grid = 64*(N/256), 512 thr, dyn LDS 131072 B.
// ---------------------------------------------------------------------------
template <int EPI>
__global__ __launch_bounds__(512, 2) void gemm256(
    const short* __restrict__ A, const short* __restrict__ BT,
    void* __restrict__ outp, const float* __restrict__ bias, int N, int K) {
  extern __shared__ __align__(16) short smem[];

  const int t = threadIdx.x;
  const int lane = t & 63, w = t >> 6;
  const int wm = w >> 2, wn = w & 3;  // wave tile: rows wm*128, cols wn*64

  const int nbn = N >> 8;
  const int oi = (int)blockIdx.x;
  const int seq = oi >> 3;
  const int bq = seq / nbn;
  const int bm = (oi & 7) * 8 + bq;
  const int bn = seq - bq * nbn;

  const int l8 = lane >> 3;
  const int lcw = ((lane & 7) ^ l8) * 8;  // swizzled chunk offset (shorts)
  const short* gA = A + (size_t)(bm * 256 + w * 8 + l8) * K + lcw;
  const short* gB = BT + (size_t)(bn * 256 + w * 8 + l8) * K + lcw;
  const int lb = w * 512;

  auto stage = [&](const short* g, int bufo, int h, int kt) {
    const int go = h * 128 * K + kt * 64;
    ld_g2l16(g + go, smem + bufo + h * 8192 + lb);                  // q = 0
    ld_g2l16(g + go + 64 * K, smem + bufo + h * 8192 + 4096 + lb);  // q = 1
  };

  const int fr = lane & 15, fc = lane >> 4;
  const int baseA = (wm * 128 + fr) * 64;
  const int baseB = (wn * 64 + fr) * 64;
  const int sl0 = (fc ^ (fr & 7)) * 8;
  const int sl1 = ((4 + fc) ^ (fr & 7)) * 8;

  f32x4 acc[8][4];
#pragma unroll
  for (int m = 0; m < 8; ++m)
#pragma unroll
    for (int n = 0; n < 4; ++n) acc[m][n] = (f32x4){0.f, 0.f, 0.f, 0.f};

  const int nt = K >> 6;

  // Prologue: tile0 -> parity-0 bufs, tile1 -> parity-1 bufs (16 loads);
  // wait to 8 so tile0 is resident while tile1 stays in flight.
  stage(gA, 0, 0, 0);
  stage(gA, 0, 1, 0);
  stage(gB, 32768, 0, 0);
  stage(gB, 32768, 1, 0);
  if (nt > 1) {
    stage(gA, 16384, 0, 1);
    stage(gA, 16384, 1, 1);
    stage(gB, 49152, 0, 1);
    stage(gB, 49152, 1, 1);
    asm volatile("s_waitcnt vmcnt(8)" ::: "memory");
  } else {
    asm volatile("s_waitcnt vmcnt(0)" ::: "memory");
  }
  __builtin_amdgcn_s_barrier();
  asm volatile("" ::: "memory");

  for (int u = 0; u < nt; ++u) {
    const bool pf = (u + 2 < nt);
    const int pa = (u & 1) << 14;  // current A buffer offset (shorts)
    const int pb = 32768 + pa;     // current B buffer offset

    // ---- read ALL fragments of tile u (24 x ds_read_b128).
    // Order a0,b0 first so the q00 MFMAs below only wait on the first 12
    // reads (compiler emits counted lgkmcnt); b1,a1 land under q00/q01.
    s16x8 a0[4][2], a1[4][2], b0[2][2], b1[2][2];
#pragma unroll
    for (int mi = 0; mi < 4; ++mi) {
      a0[mi][0] = lds_read8(smem, pa + baseA + mi * 1024 + sl0);
      a0[mi][1] = lds_read8(smem, pa + baseA + mi * 1024 + sl1);
    }
#pragma unroll
    for (int ni = 0; ni < 2; ++ni) {
      b0[ni][0] = lds_read8(smem, pb + baseB + ni * 1024 + sl0);
      b0[ni][1] = lds_read8(smem, pb + baseB + ni * 1024 + sl1);
    }
#pragma unroll
    for (int ni = 0; ni < 2; ++ni) {
      b1[ni][0] = lds_read8(smem, pb + baseB + 2048 + ni * 1024 + sl0);
      b1[ni][1] = lds_read8(smem, pb + baseB + 2048 + ni * 1024 + sl1);
    }
#pragma unroll
    for (int mi = 0; mi < 4; ++mi) {
      a1[mi][0] = lds_read8(smem, pa + baseA + 4096 + mi * 1024 + sl0);
      a1[mi][1] = lds_read8(smem, pa + baseA + 4096 + mi * 1024 + sl1);
    }

    // ---- 48 MFMA: q00, q01, q11 (consumes every LDS read above)
    __builtin_amdgcn_s_setprio(1);
#pragma unroll
    for (int mi = 0; mi < 4; ++mi)
#pragma unroll
      for (int ni = 0; ni < 2; ++ni) {
        acc[mi][ni] = MFMA16(a0[mi][0], b0[ni][0], acc[mi][ni]);
        acc[mi][ni] = MFMA16(a0[mi][1], b0[ni][1], acc[mi][ni]);
      }
#pragma unroll
    for (int mi = 0; mi < 4; ++mi)
#pragma unroll
      for (int ni = 0; ni < 2; ++ni) {
        acc[mi][2 + ni] = MFMA16(a0[mi][0], b1[ni][0], acc[mi][2 + ni]);
        acc[mi][2 + ni] = MFMA16(a0[mi][1], b1[ni][1], acc[mi][2 + ni]);
      }
#pragma unroll
    for (int mi = 0; mi < 4; ++mi)
#pragma unroll
      for (int ni = 0; ni < 2; ++ni) {
        acc[4 + mi][2 + ni] = MFMA16(a1[mi][0], b1[ni][0], acc[4 + mi][2 + ni]);
        acc[4 + mi][2 + ni] = MFMA16(a1[mi][1], b1[ni][1], acc[4 + mi][2 + ni]);
      }
    __builtin_amdgcn_s_setprio(0);

    // ---- barrier #1: all waves' reads of the current buffers are complete
    // (consumed by the MFMAs above) -> staging tile u+2 over them is legal.
    asm volatile("s_waitcnt lgkmcnt(0)" ::: "memory");  // free (consumed)
    __builtin_amdgcn_s_barrier();
    asm volatile("" ::: "memory");

    if (pf) {
      stage(gB, pb, 0, u + 2);
      stage(gB, pb, 1, u + 2);
      stage(gA, pa, 0, u + 2);
      stage(gA, pa, 1, u + 2);
    }

    // ---- 16 MFMA q10: register-only, overlaps the staging loads.
    __builtin_amdgcn_s_setprio(1);
#pragma unroll
    for (int mi = 0; mi < 4; ++mi)
#pragma unroll
      for (int ni = 0; ni < 2; ++ni) {
        acc[4 + mi][ni] = MFMA16(a1[mi][0], b0[ni][0], acc[4 + mi][ni]);
        acc[4 + mi][ni] = MFMA16(a1[mi][1], b0[ni][1], acc[4 + mi][ni]);
      }
    __builtin_amdgcn_s_setprio(0);

    if (pf) {
      // tile u+1 (issued a full K-tile ago) resident; u+2's 8 in flight
      asm volatile("s_waitcnt vmcnt(8)" ::: "memory");
    } else {
      asm volatile("s_waitcnt vmcnt(0)" ::: "memory");  // tail drain
    }
    __builtin_amdgcn_s_barrier();
    asm volatile("" ::: "memory");
  }

  const int mb = bm * 256 + wm * 128;
  const int nb = bn * 256 + wn * 64;
  const int cr = (lane >> 4) * 4;
  const int cc = lane & 15;
#pragma unroll
  for (int m = 0; m < 8; ++m) {
#pragma unroll
    for (int n = 0; n < 4; ++n) {
#pragma unroll
      for (int r = 0; r < 4; ++r) {
        const size_t row = (size_t)(mb + m * 16 + cr + r);
        const size_t col = (size_t)(nb + n * 16 + cc);
        float v = acc[m][n][r];
        if constexpr (EPI == 0) {
          ((short*)outp)[row * N + col] = f2bf(v);
        } else if constexpr (EPI == 1) {
          ((float*)outp)[row * N + col] = v;
        } else if constexpr (EPI == 2) {
          v += bias[col];
          ((short*)outp)[row * N + col] = f2bf(fast_gelu(v));
        } else {  // EPI == 4
          float prev = ((float*)outp)[row * N + col];
          v += prev;
          if (bias) v += bias[col];
          ((float*)outp)[row * N + col] = v;
        }
      }
    }
  }
}

// ---------------------------------------------------------------------------
// gemm128: tile 128x256, BK=32, 8 waves (2Mx4N, wave 64x64), LDS 48 KiB.
// __launch_bounds__(512,4): VGPR budget 128 -> no spill; 2 blocks/CU.
// grid = 128*(N/256), 512 thr, dyn LDS 49152 B.
// LDS shorts: A p0 @0, A p1 @4096, B p0 @8192, B p1 @16384.
// ---------------------------------------------------------------------------
template <int EPI>
__global__ __launch_bounds__(512, 4) void gemm128(
    const short* __restrict__ A, const short* __restrict__ BT,
    void* __restrict__ outp, const float* __restrict__ bias, int N, int K) {
  extern __shared__ __align__(16) short smem[];

  const int t = threadIdx.x;
  const int lane = t & 63, w = t >> 6;
  const int wm = w >> 2, wn = w & 3;  // wave tile: rows wm*64, cols wn*64

  // bm-banded / bn-fastest XCD mapping; nbm = 128 (M = 16384).
  const int nbn = N >> 8;
  const int oi = (int)blockIdx.x;
  const int seq = oi >> 3;
  const int bq = seq / nbn;
  const int bm = (oi & 7) * 16 + bq;
  const int bn = seq - bq * nbn;

  // Staging: lane -> (row = lane>>2 within 16-row seg, LDS slot = lane&3);
  // global chunk pre-rotated: c = ((lane&3) - ((lane>>3)&3)) & 3  (inverse
  // of the read rotation slot = (c + (row>>1)) & 3).
  const int lr = lane >> 2;
  const int lc = ((lane & 3) - ((lane >> 3) & 3)) & 3;
  const short* gA = A + (size_t)(bm * 128 + lr) * K + lc * 8;
  const short* gB = BT + (size_t)(bn * 256 + lr) * K + lc * 8;

  // Per tile: wave w stages A-seg w (1 ld) + B-segs 2w,2w+1 (2 ld).
  auto stageA = [&](int par, int kt) {
    ld_g2l16(gA + (size_t)(w * 16) * K + kt * 32, smem + par + w * 512);
  };
  auto stageB = [&](int par, int kt) {
    ld_g2l16(gB + (size_t)(2 * w * 16) * K + kt * 32,
             smem + par + 2 * w * 512);
    ld_g2l16(gB + (size_t)((2 * w + 1) * 16) * K + kt * 32,
             smem + par + (2 * w + 1) * 512);
  };

  // Fragment reads: row r, chunk fc at slot (fc + (r>>1)) & 3; 2-way per
  // 16-lane quarter (free).
  const int fr = lane & 15, fc = lane >> 4;
  const int sl = ((fc + (fr >> 1)) & 3) * 8;
  const int baseA = (wm * 64 + fr) * 32 + sl;
  const int baseB = (wn * 64 + fr) * 32 + sl;

  f32x4 acc[4][4];
#pragma unroll
  for (int m = 0; m < 4; ++m)
#pragma unroll
    for (int n = 0; n < 4; ++n) acc[m][n] = (f32x4){0.f, 0.f, 0.f, 0.f};

  const int nt = K >> 5;

  // Prologue: tile0 -> parity 0, tile1 -> parity 1 (6 loads); wait to 3.
  stageA(0, 0);
  stageB(8192, 0);
  stageA(4096, 1);
  stageB(16384, 1);
  asm volatile("s_waitcnt vmcnt(3)" ::: "memory");  // tile0 landed
  __builtin_amdgcn_s_barrier();
  asm volatile("" ::: "memory");

  for (int u = 0; u < nt; ++u) {
    const bool pf = (u + 2 < nt);
    const int pA = (u & 1) * 4096;
    const int pB = 8192 + (u & 1) * 8192;

    s16x8 a[4], b[4];
#pragma unroll
    for (int i = 0; i < 4; ++i) a[i] = lds_read8(smem, pA + baseA + i * 512);
#pragma unroll
    for (int i = 0; i < 4; ++i) b[i] = lds_read8(smem, pB + baseB + i * 512);
    asm volatile("s_waitcnt lgkmcnt(0)" ::: "memory");
    __builtin_amdgcn_s_barrier();  // all waves' reads drained -> stage safe
    asm volatile("" ::: "memory");

    if (pf) {
      stageA(pA, u + 2);
      stageB(pB, u + 2);
    }
    __builtin_amdgcn_s_setprio(1);
#pragma unroll
    for (int mi = 0; mi < 4; ++mi)
#pragma unroll
      for (int ni = 0; ni < 4; ++ni)
        acc[mi][ni] = MFMA16(a[mi], b[ni], acc[mi][ni]);
    __builtin_amdgcn_s_setprio(0);
    if (pf) {
      asm volatile("s_waitcnt vmcnt(3)" ::: "memory");  // tile u+1 resident
    } else {
      asm volatile("s_waitcnt vmcnt(0)" ::: "memory");  // tail drain
    }
    __builtin_amdgcn_s_barrier();
    asm volatile("" ::: "memory");
  }

  // Epilogue. 16x16 C/D layout: col = lane&15, row = (lane>>4)*4 + r.
  const int mb = bm * 128 + wm * 64;
  const int nb = bn * 256 + wn * 64;
  const int cr = (lane >> 4) * 4;
  const int cc = lane & 15;
#pragma unroll
  for (int m = 0; m < 4; ++m) {
#pragma unroll
    for (int n = 0; n < 4; ++n) {
#pragma unroll
      for (int r = 0; r < 4; ++r) {
        const size_t row = (size_t)(mb + m * 16 + cr + r);
        const size_t col = (size_t)(nb + n * 16 + cc);
        float v = acc[m][n][r];
        if constexpr (EPI == 0) {
          ((short*)outp)[row * N + col] = f2bf(v);
        } else if constexpr (EPI == 1) {
          ((float*)outp)[row * N + col] = v;
        } else if constexpr (EPI == 2) {
          v += bias[col];
          ((short*)outp)[row * N + col] = f2bf(fast_gelu(v));
        } else {  // EPI == 4
          float prev = ((float*)outp)[row * N + col];
          v += prev;
          if (bias) v += bias[col];
          ((float*)outp)[row * N + col] = v;
        }
      }
    }
  }
}

// ---------------------------------------------------------------------------
// Row LayerNorm over D=1024. Optional fp32 `add` (residual). Writes fp32
// and/or bf16. One block (256 thr) per row. Safe in-place (outf == in).
// ---------------------------------------------------------------------------
__global__ __launch_bounds__(256) void ln_k(
    const float* __restrict__ in, const float* __restrict__ add,
    const float* __restrict__ g, const float* __restrict__ b,
    float* __restrict__ outf, short* __restrict__ outb) {
  const int row = blockIdx.x;
  const size_t off = (size_t)row * 1024;
  const int t = threadIdx.x;
  float4 v = ((const float4*)(in + off))[t];
  if (add) {
    float4 w = ((const float4*)(add + off))[t];
    v.x += w.x; v.y += w.y; v.z += w.z; v.w += w.w;
  }
  float s = v.x + v.y + v.z + v.w;
  float ss = v.x * v.x + v.y * v.y + v.z * v.z + v.w * v.w;
#pragma unroll
  for (int o = 32; o > 0; o >>= 1) {
    s += __shfl_xor(s, o, 64);
    ss += __shfl_xor(ss, o, 64);
  }
  __shared__ float ps[4], pss[4];
  const int lane = t & 63, wave = t >> 6;
  if (lane == 0) { ps[wave] = s; pss[wave] = ss; }
  __syncthreads();
  s = ps[0] + ps[1] + ps[2] + ps[3];
  ss = pss[0] + pss[1] + pss[2] + pss[3];
  const float mean = s * (1.0f / 1024.0f);
  const float var = ss * (1.0f / 1024.0f) - mean * mean;
  const float rstd = rsqrtf(var + 1e-6f);
  const float4 gv = ((const float4*)g)[t];
  const float4 bv = ((const float4*)b)[t];
  float4 o4;
  o4.x = (v.x - mean) * rstd * gv.x + bv.x;
  o4.y = (v.y - mean) * rstd * gv.y + bv.y;
  o4.z = (v.z - mean) * rstd * gv.z + bv.z;
  o4.w = (v.w - mean) * rstd * gv.w + bv.w;
  if (outf) ((float4*)(outf + off))[t] = o4;
  if (outb) {
    s16x4 ob;
    ob[0] = f2bf(o4.x); ob[1] = f2bf(o4.y);
    ob[2] = f2bf(o4.z); ob[3] = f2bf(o4.w);
    *(s16x4*)(outb + off + t * 4) = ob;
  }
}

// ---------------------------------------------------------------------------
// Fused weight convert+transpose: all 7 weight matrices in ONE launch.
// Per 32x32 tile: W[K,N] fp32 -> WT[N,K] bf16. Segment table hardcoded.
// grid = 12288 x 256 thr.
// ---------------------------------------------------------------------------
__device__ __forceinline__ void wconv_tile(const float* __restrict__ W,
                                           short* __restrict__ WT, int K,
                                           int N, int n0, int k0,
                                           float (*tile)[33], int c, int r) {
#pragma unroll
  for (int rr = r; rr < 32; rr += 8)
    tile[rr][c] = W[(size_t)(k0 + rr) * N + n0 + c];
  __syncthreads();
#pragma unroll
  for (int rr = r; rr < 32; rr += 8)
    WT[(size_t)(n0 + rr) * K + k0 + c] = f2bf(tile[c][rr]);
}

__global__ __launch_bounds__(256) void wconv_all(
    const float* __restrict__ wq, const float* __restrict__ wk,
    const float* __restrict__ wv, const float* __restrict__ wo,
    const float* __restrict__ w1, const float* __restrict__ w2,
    short* __restrict__ WQKVT, short* __restrict__ WOT,
    short* __restrict__ W1T, short* __restrict__ W2aT,
    short* __restrict__ W2bT) {
  __shared__ float tile[32][33];
  const int t = threadIdx.x;
  const int c = t & 31, r = t >> 5;
  const int i = blockIdx.x;
  if (i < 4096) {  // wq/wk/wv/wo: 1024x1024, 32x32 tiles each
    const int seg = i >> 10, j = i & 1023;
    const int n0 = (j & 31) * 32, k0 = (j >> 5) * 32;
    const float* src = (seg == 0) ? wq : (seg == 1) ? wk : (seg == 2) ? wv : wo;
    short* dst = (seg == 3) ? WOT : WQKVT + (size_t)seg * 1024 * 1024;
    wconv_tile(src, dst, 1024, 1024, n0, k0, tile, c, r);
  } else if (i < 8192) {  // w1: K=1024, N=4096 (128 n-tiles x 32 k-tiles)
    const int j = i - 4096;
    const int n0 = (j & 127) * 32, k0 = (j >> 7) * 32;
    wconv_tile(w1, W1T, 1024, 4096, n0, k0, tile, c, r);
  } else if (i < 10240) {  // w2 rows 0-2047 -> W2aT (K=2048, N=1024)
    const int j = i - 8192;
    const int n0 = (j & 31) * 32, k0 = (j >> 5) * 32;
    wconv_tile(w2, W2aT, 2048, 1024, n0, k0, tile, c, r);
  } else {  // w2 rows 2048-4095 -> W2bT
    const int j = i - 10240;
    const int n0 = (j & 31) * 32, k0 = (j >> 5) * 32;
    wconv_tile(w2 + (size_t)2048 * 1024, W2bT, 2048, 1024, n0, k0, tile, c, r);
  }
}

// ---------------------------------------------------------------------------
// Per-token head-mixing attention + faithful-reshape scramble.
// LDS rows padded: stride 65 (= 1 mod 32) so head index h maps to distinct
// banks — unpadded stride 64 put all 16 heads on one bank = 16-way conflict
// per QK inner iteration. Ps stride 17.
// ---------------------------------------------------------------------------
__global__ __launch_bounds__(256) void attn_k(const short* __restrict__ qkv,
                                              short* __restrict__ omix) {
  __shared__ float Qs[4][16][65];
  __shared__ float Ks[4][16][65];
  __shared__ float Vs[4][16][65];
  __shared__ float Ps[4][16][17];
  const int lane = threadIdx.x & 63;
  const int wave = threadIdx.x >> 6;
  const int tok = blockIdx.x * 4 + wave;
  const short* base = qkv + (size_t)tok * 3072;

#pragma unroll
  for (int half = 0; half < 2; half++) {
    const int e = half * 512 + lane * 8;
    const int h = e >> 6, d = e & 63;
    s16x8 rq = *(const s16x8*)(base + e);
    s16x8 rk = *(const s16x8*)(base + 1024 + e);
    s16x8 rv = *(const s16x8*)(base + 2048 + e);
#pragma unroll
    for (int j = 0; j < 8; j++) {
      Qs[wave][h][d + j] = bf2f(rq[j]);
      Ks[wave][h][d + j] = bf2f(rk[j]);
      Vs[wave][h][d + j] = bf2f(rv[j]);
    }
  }
  __syncthreads();

  const int h = lane & 15;
  const int g0 = (lane >> 4) * 4;
  float sc[4] = {0.f, 0.f, 0.f, 0.f};
  for (int d = 0; d < 64; d++) {
    const float qv = Qs[wave][h][d];
#pragma unroll
    for (int i = 0; i < 4; i++) sc[i] += qv * Ks[wave][g0 + i][d];
  }
#pragma unroll
  for (int i = 0; i < 4; i++) sc[i] *= 0.125f;
  float m = fmaxf(fmaxf(sc[0], sc[1]), fmaxf(sc[2], sc[3]));
  m = fmaxf(m, __shfl_xor(m, 16, 64));
  m = fmaxf(m, __shfl_xor(m, 32, 64));
  float e[4], sum = 0.f;
#pragma unroll
  for (int i = 0; i < 4; i++) { e[i] = __expf(sc[i] - m); sum += e[i]; }
  sum += __shfl_xor(sum, 16, 64);
  sum += __shfl_xor(sum, 32, 64);
  const float inv = __frcp_rn(sum);
#pragma unroll
  for (int i = 0; i < 4; i++) Ps[wave][h][g0 + i] = e[i] * inv;
  __syncthreads();

  const int d0 = (lane >> 4) * 16;
  float o[16];
#pragma unroll
  for (int dd = 0; dd < 16; dd++) o[dd] = 0.f;
  for (int gg = 0; gg < 16; gg++) {
    const float pv = Ps[wave][h][gg];
#pragma unroll
    for (int dd = 0; dd < 16; dd++) o[dd] += pv * Vs[wave][gg][d0 + dd];
  }

  const int b = tok >> 12, t = tok & 4095;
  const size_t dst =
      ((size_t)(b * 4096 + h * 256 + (t >> 4))) * 1024 + (t & 15) * 64 + d0;
  s16x8 w0, w1;
#pragma unroll
  for (int j = 0; j < 8; j++) { w0[j] = f2bf(o[j]); w1[j] = f2bf(o[8 + j]); }
  *(s16x8*)(omix + dst) = w0;
  *(s16x8*)(omix + dst + 8) = w1;
}

// ---------------------------------------------------------------------------
extern "C" void kernel_launch(void* const* d_in, const int* in_sizes, int n_in,
                              void* d_out, int out_size, void* d_ws,
                              size_t ws_size, hipStream_t stream) {
  const float* x    = (const float*)d_in[0];
  const float* wq   = (const float*)d_in[1];
  const float* wk   = (const float*)d_in[2];
  const float* wv   = (const float*)d_in[3];
  const float* wo   = (const float*)d_in[4];
  const float* ln1g = (const float*)d_in[5];
  const float* ln1b = (const float*)d_in[6];
  const float* w1   = (const float*)d_in[7];
  const float* b1   = (const float*)d_in[8];
  const float* w2   = (const float*)d_in[9];
  const float* b2   = (const float*)d_in[10];
  const float* ln2g = (const float*)d_in[11];
  const float* ln2b = (const float*)d_in[12];
  float* out = (float*)d_out;  // [16384,1024] f32; doubles as o2/q2 buffer

  char* ws = (char*)d_ws;
  const size_t MB = 1024ull * 1024ull;
  const size_t NEEDED = 152 * MB;
  if (ws_size < NEEDED) return;  // fail-numeric instead of page-fault

  short* QKV  = (short*)(ws + 0);        // phase1 [16384,3072] bf16
  short* Q2B  = (short*)(ws + 0);        // phase2 [16384,1024] bf16
  short* Hbuf = (short*)(ws + 32 * MB);  // phase2 [16384,2048] bf16
  short* X1 = (short*)(ws + 96 * MB);    // x1, then o_mixed bf16
  short* WQKVT = (short*)(ws + 128 * MB);
  short* WOT   = (short*)(ws + 134 * MB);
  short* W1T   = (short*)(ws + 136 * MB);
  short* W2aT  = (short*)(ws + 144 * MB);
  short* W2bT  = (short*)(ws + 148 * MB);

  const dim3 B256(256);
  const dim3 B512(512);
  const unsigned LDS256 = 131072;  // gemm256
  const unsigned LDS128 = 49152;   // gemm128

  static bool attr_done = false;
  if (!attr_done) {
    attr_done = true;
    void (*k0)(const short*, const short*, void*, const float*, int, int) =
        gemm256<0>;
    (void)hipFuncSetAttribute((const void*)k0,
        hipFuncAttributeMaxDynamicSharedMemorySize, (int)LDS256);
    void (*h1)(const short*, const short*, void*, const float*, int, int) =
        gemm128<1>;
    void (*h2)(const short*, const short*, void*, const float*, int, int) =
        gemm128<2>;
    void (*h4)(const short*, const short*, void*, const float*, int, int) =
        gemm128<4>;
    (void)hipFuncSetAttribute((const void*)h1,
        hipFuncAttributeMaxDynamicSharedMemorySize, (int)LDS128);
    (void)hipFuncSetAttribute((const void*)h2,
        hipFuncAttributeMaxDynamicSharedMemorySize, (int)LDS128);
    (void)hipFuncSetAttribute((const void*)h4,
        hipFuncAttributeMaxDynamicSharedMemorySize, (int)LDS128);
  }

  // All weight conversions in one launch.
  wconv_all<<<dim3(12288), B256, 0, stream>>>(wq, wk, wv, wo, w1, w2, WQKVT,
                                              WOT, W1T, W2aT, W2bT);

  // x1 = LN1(x) -> bf16
  ln_k<<<16384, B256, 0, stream>>>(x, nullptr, ln1g, ln1b, nullptr, X1);

  // QKV = x1 @ [wq|wk|wv]   (gemm256 single-phase, grid 768)
  gemm256<0><<<dim3(768), B512, LDS256, stream>>>(X1, WQKVT, QKV, nullptr,
                                                  3072, 1024);

  // attention + scramble -> o_mixed (reuses X1 region)
  attn_k<<<4096, B256, 0, stream>>>(QKV, X1);

  // o2 = o_mixed @ wo -> f32 into d_out   (gemm128: grid 512, 2 blk/CU)
  gemm128<1><<<dim3(512), B512, LDS128, stream>>>(X1, WOT, out, nullptr,
                                                  1024, 1024);

  // q2 = LN1(o2 + x): f32 in-place in d_out, bf16 copy in Q2B
  ln_k<<<16384, B256, 0, stream>>>(out, x, ln1g, ln1b, out, Q2B);

  // FFN half A  (W1: grid 1024; W2: grid 512)
  gemm128<2><<<dim3(1024), B512, LDS128, stream>>>(Q2B, W1T, Hbuf, b1,
                                                   2048, 1024);
  gemm128<4><<<dim3(512), B512, LDS128, stream>>>(Hbuf, W2aT, out, nullptr,
                                                  1024, 2048);

  // FFN half B
  gemm128<2><<<dim3(1024), B512, LDS128, stream>>>(Q2B, W1T + 2048 * 1024,
                                                   Hbuf, b1 + 2048, 2048,
                                                   1024);
  gemm128<4><<<dim3(512), B512, LDS128, stream>>>(Hbuf, W2bT, out, b2,
                                                  1024, 2048);

  // out = LN2(y) in-place
  ln_k<<<16384, B256, 0, stream>>>(out, nullptr, ln2g, ln2b, out, nullptr);
}

// Round 9
// 776.949 us; speedup vs baseline: 1.0294x; 1.0294x over previous
//
#include <hip/hip_runtime.h>

// Encoder block: LN1 -> QKV -> per-token head-mix attention -> scramble ->
// WO -> +x,LN1 -> W1+GELU (2 halves) -> W2 accum (+b2,+q2) -> LN2 in-place.
//
// Two GEMM geometries:
//  gemm256 (rev 5 single-phase, r8): 256x256 / BK=64 / 8 waves / 128 KiB.
//    2 barriers per K-tile; QKV measured 112 us, MfmaUtil 38%. Known
//    plateau: LDS-read bursts and MFMA serialize under wave lockstep
//    (5600 cyc/tile ~= 2483 MFMA + 2300 LDS + sync); barrier-count changes
//    are neutral (r8 falsified the barrier theory). Left as-is.
//  gemm128 (rev 3 RING-3, this round): 128x256 / BK=32 / 8 waves / 72 KiB
//    LDS = 3 parity slots of 24 KB (A 8K + B 16K). ONE barrier per K-tile:
//      stage(u+2 -> slot[(u+2)%3])   // slot last read in iter u-1; those
//                                    // reads retired before barrier(u-1)
//      reads(u, slot[u%3])           // 8 ds_read_b128
//      16 MFMA ; lgkmcnt(0)
//      vmcnt(3) counted              // retires tile u+1's loads (issued
//                                    // iter u-1); u+2's 3 stay in flight
//      barrier                       // publishes tile u+1 for next iter
//    Race-free: every LDS overwrite is a full iteration (>=1 barrier) after
//    the region's last read retired. Prefetch lead = 2 tiles (~3800 cyc >>
//    900 cyc HBM miss). Halves sync cost per MFMA vs r6's 2-barrier loop.
//    __launch_bounds__(512,4): VGPR budget 128 (r5: (512,6) spilled acc).
//    2 blocks/CU (144 KB LDS <= 160): cross-block MFMA/LDS overlap.
//  XCD mapping (both): bm-banded / bn-fastest (A band L2-resident per XCD).
//
// attn_k: LDS rows padded to 65 floats (16-way bank conflict fix, r7).
// wconv_all: all 7 weight conversions in one launch (r7).
// Workspace footprint: 152 MB (d_out doubles as the f32 residual buffer).

typedef __attribute__((ext_vector_type(8))) short s16x8;
typedef __attribute__((ext_vector_type(4))) short s16x4;
typedef __attribute__((ext_vector_type(4))) float f32x4;

__device__ __forceinline__ short f2bf(float x) {
  unsigned u = __builtin_bit_cast(unsigned, x);
  u = (u + 0x7FFFu + ((u >> 16) & 1u)) >> 16;
  return (short)u;
}
__device__ __forceinline__ float bf2f(short s) {
  unsigned u = ((unsigned)(unsigned short)s) << 16;
  return __builtin_bit_cast(float, u);
}

__device__ __forceinline__ void ld_g2l16(const short* g, const short* l) {
  __builtin_amdgcn_global_load_lds(
      (const __attribute__((address_space(1))) void*)g,
      (__attribute__((address_space(3))) void*)l, 16, 0, 0);
}

// Guaranteed-DS vector read: explicit addrspace(3) so codegen emits
// ds_read_b128 (never flat_load).
__device__ __forceinline__ s16x8 lds_read8(const short* smem, int off) {
  const __attribute__((address_space(3))) short* p =
      (const __attribute__((address_space(3))) short*)smem;
  return *(const __attribute__((address_space(3))) s16x8*)(p + off);
}

// Fast GELU (tanh form via v_exp_f32; |err| ~1e-3 << bf16 noise).
__device__ __forceinline__ float fast_gelu(float v) {
  float y = 0.7978845608f * (v + 0.044715f * v * v * v);
  float ay = fabsf(y);
  float t = __expf(-2.0f * ay);
  float th = (1.0f - t) * __frcp_rn(1.0f + t);
  th = (y >= 0.f) ? th : -th;
  return 0.5f * v * (1.0f + th);
}

#define MFMA16(va, vb, vc) \
  __builtin_amdgcn_mfma_f32_16x16x32_bf16(va, vb, vc, 0, 0, 0)

// ---------------------------------------------------------------------------
// gemm256: C[M,N] = A[M,K] @ BT[N,K]^T. M=16384. N,K multiples of 256.
// EPI: 0 bf16 store; 1 f32 store; 2 +bias,GELU,bf16; 4 f32 accum (+bias).
// grid = 64*(N/256), 512 thr, dyn LDS 131072 B.  (r8 single-phase, as-is)
// ---------------------------------------------------------------------------
template <int EPI>
__global__ __launch_bounds__(512, 2) void gemm256(
    const short* __restrict__ A, const short* __restrict__ BT,
    void* __restrict__ outp, const float* __restrict__ bias, int N, int K) {
  extern __shared__ __align__(16) short smem[];

  const int t = threadIdx.x;
  const int lane = t & 63, w = t >> 6;
  const int wm = w >> 2, wn = w & 3;  // wave tile: rows wm*128, cols wn*64

  const int nbn = N >> 8;
  const int oi = (int)blockIdx.x;
  const int seq = oi >> 3;
  const int bq = seq / nbn;
  const int bm = (oi & 7) * 8 + bq;
  const int bn = seq - bq * nbn;

  const int l8 = lane >> 3;
  const int lcw = ((lane & 7) ^ l8) * 8;  // swizzled chunk offset (shorts)
  const short* gA = A + (size_t)(bm * 256 + w * 8 + l8) * K + lcw;
  const short* gB = BT + (size_t)(bn * 256 + w * 8 + l8) * K + lcw;
  const int lb = w * 512;

  auto stage = [&](const short* g, int bufo, int h, int kt) {
    const int go = h * 128 * K + kt * 64;
    ld_g2l16(g + go, smem + bufo + h * 8192 + lb);                  // q = 0
    ld_g2l16(g + go + 64 * K, smem + bufo + h * 8192 + 4096 + lb);  // q = 1
  };

  const int fr = lane & 15, fc = lane >> 4;
  const int baseA = (wm * 128 + fr) * 64;
  const int baseB = (wn * 64 + fr) * 64;
  const int sl0 = (fc ^ (fr & 7)) * 8;
  const int sl1 = ((4 + fc) ^ (fr & 7)) * 8;

  f32x4 acc[8][4];
#pragma unroll
  for (int m = 0; m < 8; ++m)
#pragma unroll
    for (int n = 0; n < 4; ++n) acc[m][n] = (f32x4){0.f, 0.f, 0.f, 0.f};

  const int nt = K >> 6;

  stage(gA, 0, 0, 0);
  stage(gA, 0, 1, 0);
  stage(gB, 32768, 0, 0);
  stage(gB, 32768, 1, 0);
  if (nt > 1) {
    stage(gA, 16384, 0, 1);
    stage(gA, 16384, 1, 1);
    stage(gB, 49152, 0, 1);
    stage(gB, 49152, 1, 1);
    asm volatile("s_waitcnt vmcnt(8)" ::: "memory");
  } else {
    asm volatile("s_waitcnt vmcnt(0)" ::: "memory");
  }
  __builtin_amdgcn_s_barrier();
  asm volatile("" ::: "memory");

  for (int u = 0; u < nt; ++u) {
    const bool pf = (u + 2 < nt);
    const int pa = (u & 1) << 14;
    const int pb = 32768 + pa;

    s16x8 a0[4][2], a1[4][2], b0[2][2], b1[2][2];
#pragma unroll
    for (int mi = 0; mi < 4; ++mi) {
      a0[mi][0] = lds_read8(smem, pa + baseA + mi * 1024 + sl0);
      a0[mi][1] = lds_read8(smem, pa + baseA + mi * 1024 + sl1);
    }
#pragma unroll
    for (int ni = 0; ni < 2; ++ni) {
      b0[ni][0] = lds_read8(smem, pb + baseB + ni * 1024 + sl0);
      b0[ni][1] = lds_read8(smem, pb + baseB + ni * 1024 + sl1);
    }
#pragma unroll
    for (int ni = 0; ni < 2; ++ni) {
      b1[ni][0] = lds_read8(smem, pb + baseB + 2048 + ni * 1024 + sl0);
      b1[ni][1] = lds_read8(smem, pb + baseB + 2048 + ni * 1024 + sl1);
    }
#pragma unroll
    for (int mi = 0; mi < 4; ++mi) {
      a1[mi][0] = lds_read8(smem, pa + baseA + 4096 + mi * 1024 + sl0);
      a1[mi][1] = lds_read8(smem, pa + baseA + 4096 + mi * 1024 + sl1);
    }

    __builtin_amdgcn_s_setprio(1);
#pragma unroll
    for (int mi = 0; mi < 4; ++mi)
#pragma unroll
      for (int ni = 0; ni < 2; ++ni) {
        acc[mi][ni] = MFMA16(a0[mi][0], b0[ni][0], acc[mi][ni]);
        acc[mi][ni] = MFMA16(a0[mi][1], b0[ni][1], acc[mi][ni]);
      }
#pragma unroll
    for (int mi = 0; mi < 4; ++mi)
#pragma unroll
      for (int ni = 0; ni < 2; ++ni) {
        acc[mi][2 + ni] = MFMA16(a0[mi][0], b1[ni][0], acc[mi][2 + ni]);
        acc[mi][2 + ni] = MFMA16(a0[mi][1], b1[ni][1], acc[mi][2 + ni]);
      }
#pragma unroll
    for (int mi = 0; mi < 4; ++mi)
#pragma unroll
      for (int ni = 0; ni < 2; ++ni) {
        acc[4 + mi][2 + ni] = MFMA16(a1[mi][0], b1[ni][0], acc[4 + mi][2 + ni]);
        acc[4 + mi][2 + ni] = MFMA16(a1[mi][1], b1[ni][1], acc[4 + mi][2 + ni]);
      }
    __builtin_amdgcn_s_setprio(0);

    asm volatile("s_waitcnt lgkmcnt(0)" ::: "memory");  // free (consumed)
    __builtin_amdgcn_s_barrier();
    asm volatile("" ::: "memory");

    if (pf) {
      stage(gB, pb, 0, u + 2);
      stage(gB, pb, 1, u + 2);
      stage(gA, pa, 0, u + 2);
      stage(gA, pa, 1, u + 2);
    }

    __builtin_amdgcn_s_setprio(1);
#pragma unroll
    for (int mi = 0; mi < 4; ++mi)
#pragma unroll
      for (int ni = 0; ni < 2; ++ni) {
        acc[4 + mi][ni] = MFMA16(a1[mi][0], b0[ni][0], acc[4 + mi][ni]);
        acc[4 + mi][ni] = MFMA16(a1[mi][1], b0[ni][1], acc[4 + mi][ni]);
      }
    __builtin_amdgcn_s_setprio(0);

    if (pf) {
      asm volatile("s_waitcnt vmcnt(8)" ::: "memory");
    } else {
      asm volatile("s_waitcnt vmcnt(0)" ::: "memory");
    }
    __builtin_amdgcn_s_barrier();
    asm volatile("" ::: "memory");
  }

  const int mb = bm * 256 + wm * 128;
  const int nb = bn * 256 + wn * 64;
  const int cr = (lane >> 4) * 4;
  const int cc = lane & 15;
#pragma unroll
  for (int m = 0; m < 8; ++m) {
#pragma unroll
    for (int n = 0; n < 4; ++n) {
#pragma unroll
      for (int r = 0; r < 4; ++r) {
        const size_t row = (size_t)(mb + m * 16 + cr + r);
        const size_t col = (size_t)(nb + n * 16 + cc);
        float v = acc[m][n][r];
        if constexpr (EPI == 0) {
          ((short*)outp)[row * N + col] = f2bf(v);
        } else if constexpr (EPI == 1) {
          ((float*)outp)[row * N + col] = v;
        } else if constexpr (EPI == 2) {
          v += bias[col];
          ((short*)outp)[row * N + col] = f2bf(fast_gelu(v));
        } else {  // EPI == 4
          float prev = ((float*)outp)[row * N + col];
          v += prev;
          if (bias) v += bias[col];
          ((float*)outp)[row * N + col] = v;
        }
      }
    }
  }
}

// ---------------------------------------------------------------------------
// gemm128 RING-3: tile 128x256, BK=32, 8 waves (2Mx4N, wave 64x64).
// LDS = 3 parity slots x 24 KB = 73728 B (A 8K @ +0, B 16K @ +4096 shorts).
// ONE barrier + one counted vmcnt per K-tile (see header comment for the
// race-freedom argument: each slot is overwritten a full iteration after
// its last read retired at that iteration's barrier).
// __launch_bounds__(512,4): VGPR budget 128 -> no spill; 2 blocks/CU.
// grid = 128*(N/256), 512 thr, dyn LDS 73728 B.
// ---------------------------------------------------------------------------
template <int EPI>
__global__ __launch_bounds__(512, 4) void gemm128(
    const short* __restrict__ A, const short* __restrict__ BT,
    void* __restrict__ outp, const float* __restrict__ bias, int N, int K) {
  extern __shared__ __align__(16) short smem[];

  const int t = threadIdx.x;
  const int lane = t & 63, w = t >> 6;
  const int wm = w >> 2, wn = w & 3;  // wave tile: rows wm*64, cols wn*64

  // bm-banded / bn-fastest XCD mapping; nbm = 128 (M = 16384).
  const int nbn = N >> 8;
  const int oi = (int)blockIdx.x;
  const int seq = oi >> 3;
  const int bq = seq / nbn;
  const int bm = (oi & 7) * 16 + bq;
  const int bn = seq - bq * nbn;

  // Staging: lane -> (row = lane>>2 within 16-row seg, LDS slot = lane&3);
  // global chunk pre-rotated: c = ((lane&3) - ((lane>>3)&3)) & 3  (inverse
  // of the read rotation slot = (c + (row>>1)) & 3).
  const int lr = lane >> 2;
  const int lc = ((lane & 3) - ((lane >> 3) & 3)) & 3;
  const short* gA = A + (size_t)(bm * 128 + lr) * K + lc * 8;
  const short* gB = BT + (size_t)(bn * 256 + lr) * K + lc * 8;

  // Per tile: wave w stages A-seg w (1 ld) + B-segs 2w,2w+1 (2 ld).
  // Parity slot base `par` (shorts): A region at par, B region at par+4096.
  auto stageT = [&](int par, int kt) {
    ld_g2l16(gA + (size_t)(w * 16) * K + kt * 32, smem + par + w * 512);
    ld_g2l16(gB + (size_t)(2 * w * 16) * K + kt * 32,
             smem + par + 4096 + 2 * w * 512);
    ld_g2l16(gB + (size_t)((2 * w + 1) * 16) * K + kt * 32,
             smem + par + 4096 + (2 * w + 1) * 512);
  };

  // Fragment reads: row r, chunk fc at slot (fc + (r>>1)) & 3; 2-way per
  // 16-lane quarter (free).
  const int fr = lane & 15, fc = lane >> 4;
  const int sl = ((fc + (fr >> 1)) & 3) * 8;
  const int baseA = (wm * 64 + fr) * 32 + sl;
  const int baseB = 4096 + (wn * 64 + fr) * 32 + sl;

  f32x4 acc[4][4];
#pragma unroll
  for (int m = 0; m < 4; ++m)
#pragma unroll
    for (int n = 0; n < 4; ++n) acc[m][n] = (f32x4){0.f, 0.f, 0.f, 0.f};

  const int nt = K >> 5;

  // Prologue: tile0 -> slot0, tile1 -> slot1 (6 loads); wait to 3 so tile0
  // is resident while tile1's 3 stay in flight; barrier publishes tile0.
  stageT(0, 0);
  stageT(12288, 1);
  asm volatile("s_waitcnt vmcnt(3)" ::: "memory");
  __builtin_amdgcn_s_barrier();
  asm volatile("" ::: "memory");

  int pcur = 0, pnxt = 12288, pprv = 24576;  // slots of u, u+1, u+2 (mod 3)
  for (int u = 0; u < nt; ++u) {
    const bool pf = (u + 2 < nt);

    // Stage tile u+2 into slot (u+2)%3 == slot read in iter u-1; those
    // reads retired (lgkmcnt 0) before iter u-1's barrier -> race-free.
    if (pf) stageT(pprv, u + 2);

    s16x8 a[4], b[4];
#pragma unroll
    for (int i = 0; i < 4; ++i)
      a[i] = lds_read8(smem, pcur + baseA + i * 512);
#pragma unroll
    for (int i = 0; i < 4; ++i)
      b[i] = lds_read8(smem, pcur + baseB + i * 512);

    __builtin_amdgcn_s_setprio(1);
#pragma unroll
    for (int mi = 0; mi < 4; ++mi)
#pragma unroll
      for (int ni = 0; ni < 4; ++ni)
        acc[mi][ni] = MFMA16(a[mi], b[ni], acc[mi][ni]);
    __builtin_amdgcn_s_setprio(0);

    asm volatile("s_waitcnt lgkmcnt(0)" ::: "memory");  // reads retired
    if (pf) {
      // retires tile u+1's 3 loads (issued iter u-1); u+2's 3 in flight
      asm volatile("s_waitcnt vmcnt(3)" ::: "memory");
    } else {
      asm volatile("s_waitcnt vmcnt(0)" ::: "memory");  // tail drain
    }
    __builtin_amdgcn_s_barrier();  // publishes tile u+1 for next iteration
    asm volatile("" ::: "memory");

    const int tmp = pcur;
    pcur = pnxt;
    pnxt = pprv;
    pprv = tmp;
  }

  // Epilogue. 16x16 C/D layout: col = lane&15, row = (lane>>4)*4 + r.
  const int mb = bm * 128 + wm * 64;
  const int nb = bn * 256 + wn * 64;
  const int cr = (lane >> 4) * 4;
  const int cc = lane & 15;
#pragma unroll
  for (int m = 0; m < 4; ++m) {
#pragma unroll
    for (int n = 0; n < 4; ++n) {
#pragma unroll
      for (int r = 0; r < 4; ++r) {
        const size_t row = (size_t)(mb + m * 16 + cr + r);
        const size_t col = (size_t)(nb + n * 16 + cc);
        float v = acc[m][n][r];
        if constexpr (EPI == 0) {
          ((short*)outp)[row * N + col] = f2bf(v);
        } else if constexpr (EPI == 1) {
          ((float*)outp)[row * N + col] = v;
        } else if constexpr (EPI == 2) {
          v += bias[col];
          ((short*)outp)[row * N + col] = f2bf(fast_gelu(v));
        } else {  // EPI == 4
          float prev = ((float*)outp)[row * N + col];
          v += prev;
          if (bias) v += bias[col];
          ((float*)outp)[row * N + col] = v;
        }
      }
    }
  }
}

// ---------------------------------------------------------------------------
// Row LayerNorm over D=1024. Optional fp32 `add` (residual). Writes fp32
// and/or bf16. One block (256 thr) per row. Safe in-place (outf == in).
// ---------------------------------------------------------------------------
__global__ __launch_bounds__(256) void ln_k(
    const float* __restrict__ in, const float* __restrict__ add,
    const float* __restrict__ g, const float* __restrict__ b,
    float* __restrict__ outf, short* __restrict__ outb) {
  const int row = blockIdx.x;
  const size_t off = (size_t)row * 1024;
  const int t = threadIdx.x;
  float4 v = ((const float4*)(in + off))[t];
  if (add) {
    float4 w = ((const float4*)(add + off))[t];
    v.x += w.x; v.y += w.y; v.z += w.z; v.w += w.w;
  }
  float s = v.x + v.y + v.z + v.w;
  float ss = v.x * v.x + v.y * v.y + v.z * v.z + v.w * v.w;
#pragma unroll
  for (int o = 32; o > 0; o >>= 1) {
    s += __shfl_xor(s, o, 64);
    ss += __shfl_xor(ss, o, 64);
  }
  __shared__ float ps[4], pss[4];
  const int lane = t & 63, wave = t >> 6;
  if (lane == 0) { ps[wave] = s; pss[wave] = ss; }
  __syncthreads();
  s = ps[0] + ps[1] + ps[2] + ps[3];
  ss = pss[0] + pss[1] + pss[2] + pss[3];
  const float mean = s * (1.0f / 1024.0f);
  const float var = ss * (1.0f / 1024.0f) - mean * mean;
  const float rstd = rsqrtf(var + 1e-6f);
  const float4 gv = ((const float4*)g)[t];
  const float4 bv = ((const float4*)b)[t];
  float4 o4;
  o4.x = (v.x - mean) * rstd * gv.x + bv.x;
  o4.y = (v.y - mean) * rstd * gv.y + bv.y;
  o4.z = (v.z - mean) * rstd * gv.z + bv.z;
  o4.w = (v.w - mean) * rstd * gv.w + bv.w;
  if (outf) ((float4*)(outf + off))[t] = o4;
  if (outb) {
    s16x4 ob;
    ob[0] = f2bf(o4.x); ob[1] = f2bf(o4.y);
    ob[2] = f2bf(o4.z); ob[3] = f2bf(o4.w);
    *(s16x4*)(outb + off + t * 4) = ob;
  }
}

// ---------------------------------------------------------------------------
// Fused weight convert+transpose: all 7 weight matrices in ONE launch.
// Per 32x32 tile: W[K,N] fp32 -> WT[N,K] bf16. Segment table hardcoded.
// grid = 12288 x 256 thr.
// ---------------------------------------------------------------------------
__device__ __forceinline__ void wconv_tile(const float* __restrict__ W,
                                           short* __restrict__ WT, int K,
                                           int N, int n0, int k0,
                                           float (*tile)[33], int c, int r) {
#pragma unroll
  for (int rr = r; rr < 32; rr += 8)
    tile[rr][c] = W[(size_t)(k0 + rr) * N + n0 + c];
  __syncthreads();
#pragma unroll
  for (int rr = r; rr < 32; rr += 8)
    WT[(size_t)(n0 + rr) * K + k0 + c] = f2bf(tile[c][rr]);
}

__global__ __launch_bounds__(256) void wconv_all(
    const float* __restrict__ wq, const float* __restrict__ wk,
    const float* __restrict__ wv, const float* __restrict__ wo,
    const float* __restrict__ w1, const float* __restrict__ w2,
    short* __restrict__ WQKVT, short* __restrict__ WOT,
    short* __restrict__ W1T, short* __restrict__ W2aT,
    short* __restrict__ W2bT) {
  __shared__ float tile[32][33];
  const int t = threadIdx.x;
  const int c = t & 31, r = t >> 5;
  const int i = blockIdx.x;
  if (i < 4096) {  // wq/wk/wv/wo: 1024x1024, 32x32 tiles each
    const int seg = i >> 10, j = i & 1023;
    const int n0 = (j & 31) * 32, k0 = (j >> 5) * 32;
    const float* src = (seg == 0) ? wq : (seg == 1) ? wk : (seg == 2) ? wv : wo;
    short* dst = (seg == 3) ? WOT : WQKVT + (size_t)seg * 1024 * 1024;
    wconv_tile(src, dst, 1024, 1024, n0, k0, tile, c, r);
  } else if (i < 8192) {  // w1: K=1024, N=4096 (128 n-tiles x 32 k-tiles)
    const int j = i - 4096;
    const int n0 = (j & 127) * 32, k0 = (j >> 7) * 32;
    wconv_tile(w1, W1T, 1024, 4096, n0, k0, tile, c, r);
  } else if (i < 10240) {  // w2 rows 0-2047 -> W2aT (K=2048, N=1024)
    const int j = i - 8192;
    const int n0 = (j & 31) * 32, k0 = (j >> 5) * 32;
    wconv_tile(w2, W2aT, 2048, 1024, n0, k0, tile, c, r);
  } else {  // w2 rows 2048-4095 -> W2bT
    const int j = i - 10240;
    const int n0 = (j & 31) * 32, k0 = (j >> 5) * 32;
    wconv_tile(w2 + (size_t)2048 * 1024, W2bT, 2048, 1024, n0, k0, tile, c, r);
  }
}

// ---------------------------------------------------------------------------
// Per-token head-mixing attention + faithful-reshape scramble.
// LDS rows padded: stride 65 (= 1 mod 32) so head index h maps to distinct
// banks — unpadded stride 64 put all 16 heads on one bank = 16-way conflict
// per QK inner iteration. Ps stride 17.
// ---------------------------------------------------------------------------
__global__ __launch_bounds__(256) void attn_k(const short* __restrict__ qkv,
                                              short* __restrict__ omix) {
  __shared__ float Qs[4][16][65];
  __shared__ float Ks[4][16][65];
  __shared__ float Vs[4][16][65];
  __shared__ float Ps[4][16][17];
  const int lane = threadIdx.x & 63;
  const int wave = threadIdx.x >> 6;
  const int tok = blockIdx.x * 4 + wave;
  const short* base = qkv + (size_t)tok * 3072;

#pragma unroll
  for (int half = 0; half < 2; half++) {
    const int e = half * 512 + lane * 8;
    const int h = e >> 6, d = e & 63;
    s16x8 rq = *(const s16x8*)(base + e);
    s16x8 rk = *(const s16x8*)(base + 1024 + e);
    s16x8 rv = *(const s16x8*)(base + 2048 + e);
#pragma unroll
    for (int j = 0; j < 8; j++) {
      Qs[wave][h][d + j] = bf2f(rq[j]);
      Ks[wave][h][d + j] = bf2f(rk[j]);
      Vs[wave][h][d + j] = bf2f(rv[j]);
    }
  }
  __syncthreads();

  const int h = lane & 15;
  const int g0 = (lane >> 4) * 4;
  float sc[4] = {0.f, 0.f, 0.f, 0.f};
  for (int d = 0; d < 64; d++) {
    const float qv = Qs[wave][h][d];
#pragma unroll
    for (int i = 0; i < 4; i++) sc[i] += qv * Ks[wave][g0 + i][d];
  }
#pragma unroll
  for (int i = 0; i < 4; i++) sc[i] *= 0.125f;
  float m = fmaxf(fmaxf(sc[0], sc[1]), fmaxf(sc[2], sc[3]));
  m = fmaxf(m, __shfl_xor(m, 16, 64));
  m = fmaxf(m, __shfl_xor(m, 32, 64));
  float e[4], sum = 0.f;
#pragma unroll
  for (int i = 0; i < 4; i++) { e[i] = __expf(sc[i] - m); sum += e[i]; }
  sum += __shfl_xor(sum, 16, 64);
  sum += __shfl_xor(sum, 32, 64);
  const float inv = __frcp_rn(sum);
#pragma unroll
  for (int i = 0; i < 4; i++) Ps[wave][h][g0 + i] = e[i] * inv;
  __syncthreads();

  const int d0 = (lane >> 4) * 16;
  float o[16];
#pragma unroll
  for (int dd = 0; dd < 16; dd++) o[dd] = 0.f;
  for (int gg = 0; gg < 16; gg++) {
    const float pv = Ps[wave][h][gg];
#pragma unroll
    for (int dd = 0; dd < 16; dd++) o[dd] += pv * Vs[wave][gg][d0 + dd];
  }

  const int b = tok >> 12, t = tok & 4095;
  const size_t dst =
      ((size_t)(b * 4096 + h * 256 + (t >> 4))) * 1024 + (t & 15) * 64 + d0;
  s16x8 w0, w1;
#pragma unroll
  for (int j = 0; j < 8; j++) { w0[j] = f2bf(o[j]); w1[j] = f2bf(o[8 + j]); }
  *(s16x8*)(omix + dst) = w0;
  *(s16x8*)(omix + dst + 8) = w1;
}

// ---------------------------------------------------------------------------
extern "C" void kernel_launch(void* const* d_in, const int* in_sizes, int n_in,
                              void* d_out, int out_size, void* d_ws,
                              size_t ws_size, hipStream_t stream) {
  const float* x    = (const float*)d_in[0];
  const float* wq   = (const float*)d_in[1];
  const float* wk   = (const float*)d_in[2];
  const float* wv   = (const float*)d_in[3];
  const float* wo   = (const float*)d_in[4];
  const float* ln1g = (const float*)d_in[5];
  const float* ln1b = (const float*)d_in[6];
  const float* w1   = (const float*)d_in[7];
  const float* b1   = (const float*)d_in[8];
  const float* w2   = (const float*)d_in[9];
  const float* b2   = (const float*)d_in[10];
  const float* ln2g = (const float*)d_in[11];
  const float* ln2b = (const float*)d_in[12];
  float* out = (float*)d_out;  // [16384,1024] f32; doubles as o2/q2 buffer

  char* ws = (char*)d_ws;
  const size_t MB = 1024ull * 1024ull;
  const size_t NEEDED = 152 * MB;
  if (ws_size < NEEDED) return;  // fail-numeric instead of page-fault

  short* QKV  = (short*)(ws + 0);        // phase1 [16384,3072] bf16
  short* Q2B  = (short*)(ws + 0);        // phase2 [16384,1024] bf16
  short* Hbuf = (short*)(ws + 32 * MB);  // phase2 [16384,2048] bf16
  short* X1 = (short*)(ws + 96 * MB);    // x1, then o_mixed bf16
  short* WQKVT = (short*)(ws + 128 * MB);
  short* WOT   = (short*)(ws + 134 * MB);
  short* W1T   = (short*)(ws + 136 * MB);
  short* W2aT  = (short*)(ws + 144 * MB);
  short* W2bT  = (short*)(ws + 148 * MB);

  const dim3 B256(256);
  const dim3 B512(512);
  const unsigned LDS256 = 131072;  // gemm256
  const unsigned LDS128 = 73728;   // gemm128 ring-3

  static bool attr_done = false;
  if (!attr_done) {
    attr_done = true;
    void (*k0)(const short*, const short*, void*, const float*, int, int) =
        gemm256<0>;
    (void)hipFuncSetAttribute((const void*)k0,
        hipFuncAttributeMaxDynamicSharedMemorySize, (int)LDS256);
    void (*h1)(const short*, const short*, void*, const float*, int, int) =
        gemm128<1>;
    void (*h2)(const short*, const short*, void*, const float*, int, int) =
        gemm128<2>;
    void (*h4)(const short*, const short*, void*, const float*, int, int) =
        gemm128<4>;
    (void)hipFuncSetAttribute((const void*)h1,
        hipFuncAttributeMaxDynamicSharedMemorySize, (int)LDS128);
    (void)hipFuncSetAttribute((const void*)h2,
        hipFuncAttributeMaxDynamicSharedMemorySize, (int)LDS128);
    (void)hipFuncSetAttribute((const void*)h4,
        hipFuncAttributeMaxDynamicSharedMemorySize, (int)LDS128);
  }

  // All weight conversions in one launch.
  wconv_all<<<dim3(12288), B256, 0, stream>>>(wq, wk, wv, wo, w1, w2, WQKVT,
                                              WOT, W1T, W2aT, W2bT);

  // x1 = LN1(x) -> bf16
  ln_k<<<16384, B256, 0, stream>>>(x, nullptr, ln1g, ln1b, nullptr, X1);

  // QKV = x1 @ [wq|wk|wv]   (gemm256 single-phase, grid 768)
  gemm256<0><<<dim3(768), B512, LDS256, stream>>>(X1, WQKVT, QKV, nullptr,
                                                  3072, 1024);

  // attention + scramble -> o_mixed (reuses X1 region)
  attn_k<<<4096, B256, 0, stream>>>(QKV, X1);

  // o2 = o_mixed @ wo -> f32 into d_out   (gemm128 ring-3: grid 512)
  gemm128<1><<<dim3(512), B512, LDS128, stream>>>(X1, WOT, out, nullptr,
                                                  1024, 1024);

  // q2 = LN1(o2 + x): f32 in-place in d_out, bf16 copy in Q2B
  ln_k<<<16384, B256, 0, stream>>>(out, x, ln1g, ln1b, out, Q2B);

  // FFN half A  (W1: grid 1024; W2: grid 512)
  gemm128<2><<<dim3(1024), B512, LDS128, stream>>>(Q2B, W1T, Hbuf, b1,
                                                   2048, 1024);
  gemm128<4><<<dim3(512), B512, LDS128, stream>>>(Hbuf, W2aT, out, nullptr,
                                                  1024, 2048);

  // FFN half B
  gemm128<2><<<dim3(1024), B512, LDS128, stream>>>(Q2B, W1T + 2048 * 1024,
                                                   Hbuf, b1 + 2048, 2048,
                                                   1024);
  gemm128<4><<<dim3(512), B512, LDS128, stream>>>(Hbuf, W2bT, out, b2,
                                                  1024, 2048);

  // out = LN2(y) in-place
  ln_k<<<16384, B256, 0, stream>>>(out, nullptr, ln2g, ln2b, out, nullptr);
}